// Round 14
// baseline (1320.035 us; speedup 1.0000x reference)
//
#include <hip/hip_runtime.h>
#include <hip/hip_bf16.h>

// ---- problem constants ----
#define BATCH 16
#define CIN   12
#define HIMG  512
#define WIMG  512
#define OCH   768
#define KDIM  256            // 16*16 patch
#define HW    (HIMG*WIMG)    // 262144
#define NPATCH 1024          // 32*32 patches per batch

#define PACK_BLOCKS 96       // 24576 pack units / 256
#define MEAN_BLOCKS 4096     // 16 batches * 32 stripes * 8 blocks
#define NCNT 2048            // counters: (b,s) group * 4 o-quarters
#define TARGET 104           // 8 mean blocks + 96 pack blocks per counter

typedef __attribute__((ext_vector_type(8))) short short8;   // 8 bf16
typedef __attribute__((ext_vector_type(4))) float f32x4;

// ---------------------------------------------------------------------------
// pack: w f32 -> bf16 in MFMA fragment-lane order (R2-validated):
//   packed[u], u=(ot*8+kk)*64+lane holds w[ot*16+(lane&15)][kk*32+(lane>>4)*8+j]
// ---------------------------------------------------------------------------
__device__ __forceinline__ void pack_body(int u, const float* __restrict__ w,
                                          short8* __restrict__ wbp) {
    int lane = u & 63;
    int kk   = (u >> 6) & 7;
    int ot   = u >> 9;                               // 0..47
    int o = ot * 16 + (lane & 15);
    int k = kk * 32 + (lane >> 4) * 8;
    const float* src = w + (size_t)o * KDIM + k;
    f32x4 v0 = *reinterpret_cast<const f32x4*>(src);
    f32x4 v1 = *reinterpret_cast<const f32x4*>(src + 4);
    union { short8 s; __hip_bfloat16 h[8]; } t;
    t.h[0] = __float2bfloat16(v0.x);
    t.h[1] = __float2bfloat16(v0.y);
    t.h[2] = __float2bfloat16(v0.z);
    t.h[3] = __float2bfloat16(v0.w);
    t.h[4] = __float2bfloat16(v1.x);
    t.h[5] = __float2bfloat16(v1.y);
    t.h[6] = __float2bfloat16(v1.z);
    t.h[7] = __float2bfloat16(v1.w);
    wbp[u] = t.s;
}

// ---------------------------------------------------------------------------
// gemm unit (g2 = b*32 + stripe s, q = o-quarter): 32 patches x 192 o-chans,
// 256 threads = 4 waves; wave wv owns 48 o (3 frags) x 32 m (2 frags).
// LDS-free (R12/R13-validated): A = coalesced 1 KiB wave loads from packed
// weights; B = direct per-lane 16 B loads from xm.
// ---------------------------------------------------------------------------
__device__ __forceinline__ void gemm_unit(int g2, int q, int tid,
                                          const short8* __restrict__ wbp,
                                          const __hip_bfloat16* __restrict__ xm,
                                          const float* __restrict__ bias,
                                          float* __restrict__ out) {
    const int b = g2 >> 5, s = g2 & 31;
    const int lane = tid & 63;
    const int wv   = tid >> 6;           // 0..3
    const int lrow = lane & 15;
    const int lg   = lane >> 4;

    const __hip_bfloat16* xmb = xm + (size_t)b * HW + s * (16 * WIMG)
                                + (lg >> 1) * WIMG + (lg & 1) * 8;
    f32x4 acc[3][2] = {};
    const short8* wp = wbp + (size_t)(q * 12 + wv * 3) * 8 * 64 + lane;

    #pragma unroll
    for (int kk = 0; kk < 8; ++kk) {
        short8 af[3], bf[2];
        #pragma unroll
        for (int fo = 0; fo < 3; ++fo)
            af[fo] = wp[(size_t)(fo * 8 + kk) * 64];
        #pragma unroll
        for (int fm = 0; fm < 2; ++fm)
            bf[fm] = *reinterpret_cast<const short8*>(
                xmb + (fm * 16 + lrow) * 16 + kk * (2 * WIMG));
        #pragma unroll
        for (int fo = 0; fo < 3; ++fo)
            #pragma unroll
            for (int fm = 0; fm < 2; ++fm)
                acc[fo][fm] = __builtin_amdgcn_mfma_f32_16x16x32_bf16(
                    af[fo], bf[fm], acc[fo][fm], 0, 0, 0);
    }

    // epilogue: D row = o ((lane>>4)*4 + reg), col = m (lane&15)
    float* ob = out + (size_t)b * OCH * NPATCH + s * 32;
    #pragma unroll
    for (int fo = 0; fo < 3; ++fo) {
        const int obase = q * 192 + wv * 48 + fo * 16 + lg * 4;
        #pragma unroll
        for (int r = 0; r < 4; ++r) {
            const int o = obase + r;
            const float bv = bias[o];
            float* orow = ob + (size_t)o * NPATCH;
            #pragma unroll
            for (int fm = 0; fm < 2; ++fm)
                orow[fm * 16 + lrow] = acc[fo][fm][r] + bv;
        }
    }
}

// ---------------------------------------------------------------------------
// Fused kernel: pack (blocks 0..95) + mean (96..4191) + GEMM-by-finisher.
// Counter c = g2*4 + q, target 104 = 8 mean blocks of stripe g2 + 96 pack
// blocks (pack thread t contributes to counters t*8..t*8+7).
// Contributor protocol: work -> __threadfence (release) -> __syncthreads ->
// atomicAdd; the add that reaches TARGET enqueues the unit in LDS; after a
// final __syncthreads the whole block executes queued units (acquire fence
// first).  No waiting anywhere -> no deadlock; each unit exactly once ->
// deterministic output values.
// ---------------------------------------------------------------------------
__global__ __launch_bounds__(256) void fused_kernel(
        const float* __restrict__ x, const float* __restrict__ w,
        const float* __restrict__ bias, float* __restrict__ out,
        __hip_bfloat16* __restrict__ xm, short8* __restrict__ wbp,
        unsigned int* __restrict__ cnt) {
    __shared__ int qn;
    __shared__ unsigned short qlist[1024];
    const int tid = threadIdx.x;
    const int bid = blockIdx.x;
    if (tid == 0) qn = 0;

    if (bid < PACK_BLOCKS) {
        pack_body(bid * 256 + tid, w, wbp);
        __threadfence();                 // release pack stores (device scope)
        __syncthreads();                 // qn init + all block stores fenced
        #pragma unroll
        for (int j = 0; j < 8; ++j) {
            const int c = tid * 8 + j;
            unsigned old = atomicAdd(&cnt[c], 1u);
            if (old == TARGET - 1) {
                int i = atomicAdd(&qn, 1);
                qlist[i] = (unsigned short)c;
            }
        }
    } else {
        const int mb  = bid - PACK_BLOCKS;
        const int g2  = mb >> 3;         // (b,s) group 0..511
        const int sub = mb & 7;          // 2-row sub-block
        const int b = g2 >> 5, s = g2 & 31;
        const int row = s * 16 + sub * 2 + (tid >> 7);
        const int c4  = tid & 127;       // float4 col
        const float* px = x + (size_t)b * CIN * HW + (size_t)row * WIMG + c4 * 4;
        float sx = 0.f, sy = 0.f, sz = 0.f, sw = 0.f;
        #pragma unroll
        for (int c = 0; c < CIN; ++c) {
            f32x4 v = *reinterpret_cast<const f32x4*>(px + (size_t)c * HW);
            sx += v.x; sy += v.y; sz += v.z; sw += v.w;
        }
        const float inv = 1.0f / 12.0f;
        union { ushort4 u4; __hip_bfloat16 h[4]; } o;
        o.h[0] = __float2bfloat16(sx * inv);
        o.h[1] = __float2bfloat16(sy * inv);
        o.h[2] = __float2bfloat16(sz * inv);
        o.h[3] = __float2bfloat16(sw * inv);
        *reinterpret_cast<ushort4*>(
            xm + (size_t)b * HW + (size_t)row * WIMG + c4 * 4) = o.u4;
        __threadfence();                 // release xm stores (device scope)
        __syncthreads();
        if (tid == 0) {
            #pragma unroll
            for (int q = 0; q < 4; ++q) {
                unsigned old = atomicAdd(&cnt[g2 * 4 + q], 1u);
                if (old == TARGET - 1) {
                    qlist[qn] = (unsigned short)(g2 * 4 + q);
                    qn++;
                }
            }
        }
    }

    __syncthreads();                     // publish qn/qlist block-wide
    const int n = qn;
    if (n == 0) return;
    __threadfence();                     // acquire xm/wbp from other blocks
    for (int i = 0; i < n; ++i) {
        const int c = qlist[i];
        gemm_unit(c >> 2, c & 3, tid, wbp, xm, bias, out);
    }
}

// ---------------------------------------------------------------------------
extern "C" void kernel_launch(void* const* d_in, const int* in_sizes, int n_in,
                              void* d_out, int out_size, void* d_ws, size_t ws_size,
                              hipStream_t stream) {
    const float* x    = (const float*)d_in[0];
    const float* w    = (const float*)d_in[1];
    const float* bias = (const float*)d_in[2];
    float* out = (float*)d_out;

    __hip_bfloat16* xm = (__hip_bfloat16*)d_ws;                            // 8 MiB
    short8* wbp = (short8*)((char*)d_ws + (size_t)BATCH * HW * 2);         // 384 KiB
    unsigned int* cnt = (unsigned int*)((char*)d_ws + (size_t)BATCH * HW * 2
                                        + (size_t)OCH * KDIM * 2);         // 8 KiB

    hipMemsetAsync(cnt, 0, NCNT * sizeof(unsigned int), stream);
    fused_kernel<<<PACK_BLOCKS + MEAN_BLOCKS, 256, 0, stream>>>(
        x, w, bias, out, xm, wbp, cnt);
}

// Round 15
// 52.352 us; speedup vs baseline: 25.2146x; 25.2146x over previous
//
#include <hip/hip_runtime.h>
#include <hip/hip_bf16.h>

// ---- problem constants ----
#define BATCH 16
#define CIN   12
#define HIMG  512
#define WIMG  512
#define OCH   768
#define KDIM  256            // 16*16 patch
#define HW    (HIMG*WIMG)    // 262144
#define NPATCH 1024          // 32*32 patches per batch

#define MEAN_BLOCKS 4096     // BATCH*HW/4/256
#define PACK_BLOCKS 96       // OCH*KDIM/8/256

typedef __attribute__((ext_vector_type(8))) short short8;   // 8 bf16 = 4 VGPRs
typedef __attribute__((ext_vector_type(4))) float f32x4;

// ---------------------------------------------------------------------------
// Kernel A (merged): channel-mean (blocks 0..4095) + weight pack (4096..4191).
// mean: xm[b][h][w] = mean_c x[b][c][h][w], f32 -> bf16 (R1-validated body).
// pack: w f32 -> bf16 in MFMA fragment-lane order (R2-validated):
//   packed[u], u = (ot*8 + kk)*64 + lane holds
//   w[ot*16 + (lane&15)][kk*32 + (lane>>4)*8 + j], j=0..7.
// ---------------------------------------------------------------------------
__global__ __launch_bounds__(256) void mean_pack_kernel(
        const float* __restrict__ x, __hip_bfloat16* __restrict__ xm,
        const float* __restrict__ w, short8* __restrict__ wbp) {
    const int bid = blockIdx.x;
    if (bid < MEAN_BLOCKS) {
        int idx = bid * 256 + threadIdx.x;              // float4 index
        int b = idx >> 16;                              // 65536 float4 per image
        int pos = (idx & 65535) << 2;
        const float* px = x + (size_t)b * CIN * HW + pos;
        float sx = 0.f, sy = 0.f, sz = 0.f, sw = 0.f;
        #pragma unroll
        for (int c = 0; c < CIN; ++c) {
            f32x4 v = *reinterpret_cast<const f32x4*>(px + (size_t)c * HW);
            sx += v.x; sy += v.y; sz += v.z; sw += v.w;
        }
        const float inv = 1.0f / 12.0f;
        union { ushort4 u4; __hip_bfloat16 h[4]; } o;
        o.h[0] = __float2bfloat16(sx * inv);
        o.h[1] = __float2bfloat16(sy * inv);
        o.h[2] = __float2bfloat16(sz * inv);
        o.h[3] = __float2bfloat16(sw * inv);
        *reinterpret_cast<ushort4*>(xm + (size_t)idx * 4) = o.u4;
    } else {
        int u = (bid - MEAN_BLOCKS) * 256 + threadIdx.x;   // 0..24575
        int lane = u & 63;
        int kk   = (u >> 6) & 7;
        int ot   = u >> 9;                                 // 0..47
        int o = ot * 16 + (lane & 15);
        int k = kk * 32 + (lane >> 4) * 8;
        const float* src = w + (size_t)o * KDIM + k;
        f32x4 v0 = *reinterpret_cast<const f32x4*>(src);
        f32x4 v1 = *reinterpret_cast<const f32x4*>(src + 4);
        union { short8 s; __hip_bfloat16 h[8]; } t;
        t.h[0] = __float2bfloat16(v0.x);
        t.h[1] = __float2bfloat16(v0.y);
        t.h[2] = __float2bfloat16(v0.z);
        t.h[3] = __float2bfloat16(v0.w);
        t.h[4] = __float2bfloat16(v1.x);
        t.h[5] = __float2bfloat16(v1.y);
        t.h[6] = __float2bfloat16(v1.z);
        t.h[7] = __float2bfloat16(v1.w);
        wbp[u] = t.s;
    }
}

// ---------------------------------------------------------------------------
// Kernel B: LDS-free patch-embedding GEMM, HIGH-OCCUPANCY GRID.
// 1024 blocks x 256 threads (4 waves), __launch_bounds__(256,4): VGPR<=128,
// no spill (live set ~100), 4 blocks/CU resident, 2x block count vs R8/R12.
// Block = (batch b, stripe-pair sp, o-quarter oq): 64 patches x 192 o-chans.
// Wave wv owns o-range oq*192 + wv*48 (3 frags) x all 64 patches (4 frags),
// acc[3][4] = 48 VGPR, K = 256 in 8 steps.
//   A-fragments: coalesced 1 KiB wave loads from L2-resident packed weights.
//   B-fragments: direct per-lane 16 B loads from L2/L3-resident xm
//     (R12-validated layout: lane m = lane&15 within fragment; k-slice from
//     lg: row r = kk*2+(lg>>1), s0 = (lg&1)*8).
// No barriers; compiler pipelines the whole K-loop.
// ---------------------------------------------------------------------------
__global__ __launch_bounds__(256, 4) void gemm_kernel(
        const short8* __restrict__ wbp,          // packed weights
        const __hip_bfloat16* __restrict__ xm,   // [B][H][W] mean image
        const float* __restrict__ bias,
        float* __restrict__ out) {               // [B][O][32][32]
    const int tid = threadIdx.x;
    const int b  = blockIdx.x >> 6;
    const int sp = (blockIdx.x >> 2) & 15;   // stripe pair (64 patches)
    const int oq = blockIdx.x & 3;           // o-quarter (192 channels)

    const int lane = tid & 63;
    const int wv   = tid >> 6;           // 0..3
    const int lrow = lane & 15;
    const int lg   = lane >> 4;

    // B base: b, stripe-pair, k-slice part from lg (row (lg>>1), col (lg&1)*8)
    const __hip_bfloat16* xmb = xm + (size_t)b * HW + sp * (32 * WIMG)
                                + (lg >> 1) * WIMG + (lg & 1) * 8;
    // per-fragment m offsets: m = fm*16 + lrow -> stripe si = m>>5, col j = m&31
    int e0[4];
    #pragma unroll
    for (int fm = 0; fm < 4; ++fm) {
        const int ml = fm * 16 + lrow;
        e0[fm] = (ml >> 5) * (16 * WIMG) + (ml & 31) * 16;
    }

    f32x4 acc[3][4] = {};
    // weight 16-row tile base: (oq*192 + wv*48)/16 = oq*12 + wv*3
    const short8* wp = wbp + (size_t)(oq * 12 + wv * 3) * 8 * 64 + lane;

    #pragma unroll
    for (int kk = 0; kk < 8; ++kk) {
        short8 af[3], bf[4];
        #pragma unroll
        for (int fo = 0; fo < 3; ++fo)
            af[fo] = wp[(size_t)(fo * 8 + kk) * 64];
        #pragma unroll
        for (int fm = 0; fm < 4; ++fm)
            bf[fm] = *reinterpret_cast<const short8*>(xmb + e0[fm] + kk * (2 * WIMG));
        #pragma unroll
        for (int fo = 0; fo < 3; ++fo)
            #pragma unroll
            for (int fm = 0; fm < 4; ++fm)
                acc[fo][fm] = __builtin_amdgcn_mfma_f32_16x16x32_bf16(af[fo], bf[fm], acc[fo][fm], 0, 0, 0);
    }

    // ---- epilogue: D row = o ((lane>>4)*4 + reg), col = m (lane&15) ----
    float* ob = out + (size_t)b * OCH * NPATCH + sp * 64;
    #pragma unroll
    for (int fo = 0; fo < 3; ++fo) {
        const int obase = oq * 192 + wv * 48 + fo * 16 + lg * 4;
        #pragma unroll
        for (int r = 0; r < 4; ++r) {
            const int o = obase + r;
            const float bv = bias[o];
            float* orow = ob + (size_t)o * NPATCH;
            #pragma unroll
            for (int fm = 0; fm < 4; ++fm)
                orow[fm * 16 + lrow] = acc[fo][fm][r] + bv;
        }
    }
}

// ---------------------------------------------------------------------------
extern "C" void kernel_launch(void* const* d_in, const int* in_sizes, int n_in,
                              void* d_out, int out_size, void* d_ws, size_t ws_size,
                              hipStream_t stream) {
    const float* x    = (const float*)d_in[0];
    const float* w    = (const float*)d_in[1];
    const float* bias = (const float*)d_in[2];
    float* out = (float*)d_out;

    __hip_bfloat16* xm = (__hip_bfloat16*)d_ws;                                   // 8 MiB
    short8* wbp = (short8*)((char*)d_ws + (size_t)BATCH * HW * 2);                // 384 KiB

    mean_pack_kernel<<<MEAN_BLOCKS + PACK_BLOCKS, 256, 0, stream>>>(x, xm, w, wbp);
    gemm_kernel<<<1024, 256, 0, stream>>>(wbp, xm, bias, out);
}

// Round 16
// 50.921 us; speedup vs baseline: 25.9230x; 1.0281x over previous
//
#include <hip/hip_runtime.h>
#include <hip/hip_bf16.h>

// ---- problem constants ----
#define BATCH 16
#define CIN   12
#define HIMG  512
#define WIMG  512
#define OCH   768
#define KDIM  256            // 16*16 patch
#define HW    (HIMG*WIMG)    // 262144
#define NPATCH 1024          // 32*32 patches per batch

#define MEAN_BLOCKS 4096     // BATCH*HW/4/256
#define PACK_BLOCKS 96       // OCH*KDIM/8/256

typedef __attribute__((ext_vector_type(8))) short short8;   // 8 bf16 = 4 VGPRs
typedef __attribute__((ext_vector_type(4))) float f32x4;

// ---------------------------------------------------------------------------
// Kernel A (merged): channel-mean (blocks 0..4095) + weight pack (4096..4191).
// mean: xm[b][h][w] = mean_c x[b][c][h][w], f32 -> bf16 (R1-validated body).
// pack: w f32 -> bf16 in MFMA fragment-lane order (R2-validated):
//   packed[u], u = (ot*8 + kk)*64 + lane holds
//   w[ot*16 + (lane&15)][kk*32 + (lane>>4)*8 + j], j=0..7.
// ---------------------------------------------------------------------------
__global__ __launch_bounds__(256) void mean_pack_kernel(
        const float* __restrict__ x, __hip_bfloat16* __restrict__ xm,
        const float* __restrict__ w, short8* __restrict__ wbp) {
    const int bid = blockIdx.x;
    if (bid < MEAN_BLOCKS) {
        int idx = bid * 256 + threadIdx.x;              // float4 index
        int b = idx >> 16;                              // 65536 float4 per image
        int pos = (idx & 65535) << 2;
        const float* px = x + (size_t)b * CIN * HW + pos;
        float sx = 0.f, sy = 0.f, sz = 0.f, sw = 0.f;
        #pragma unroll
        for (int c = 0; c < CIN; ++c) {
            f32x4 v = *reinterpret_cast<const f32x4*>(px + (size_t)c * HW);
            sx += v.x; sy += v.y; sz += v.z; sw += v.w;
        }
        const float inv = 1.0f / 12.0f;
        union { ushort4 u4; __hip_bfloat16 h[4]; } o;
        o.h[0] = __float2bfloat16(sx * inv);
        o.h[1] = __float2bfloat16(sy * inv);
        o.h[2] = __float2bfloat16(sz * inv);
        o.h[3] = __float2bfloat16(sw * inv);
        *reinterpret_cast<ushort4*>(xm + (size_t)idx * 4) = o.u4;
    } else {
        int u = (bid - MEAN_BLOCKS) * 256 + threadIdx.x;   // 0..24575
        int lane = u & 63;
        int kk   = (u >> 6) & 7;
        int ot   = u >> 9;                                 // 0..47
        int o = ot * 16 + (lane & 15);
        int k = kk * 32 + (lane >> 4) * 8;
        const float* src = w + (size_t)o * KDIM + k;
        f32x4 v0 = *reinterpret_cast<const f32x4*>(src);
        f32x4 v1 = *reinterpret_cast<const f32x4*>(src + 4);
        union { short8 s; __hip_bfloat16 h[8]; } t;
        t.h[0] = __float2bfloat16(v0.x);
        t.h[1] = __float2bfloat16(v0.y);
        t.h[2] = __float2bfloat16(v0.z);
        t.h[3] = __float2bfloat16(v0.w);
        t.h[4] = __float2bfloat16(v1.x);
        t.h[5] = __float2bfloat16(v1.y);
        t.h[6] = __float2bfloat16(v1.z);
        t.h[7] = __float2bfloat16(v1.w);
        wbp[u] = t.s;
    }
}

// ---------------------------------------------------------------------------
// Kernel B: patch-embedding GEMM, 512 blocks x 512 threads (8 waves).
// Block = (batch b, stripe-PAIR sp, o-half oh): 64 patches x 384 o-channels.
// Wave wv owns o-range oh*384 + wv*48 .. +48 (3 frags) x 64 patches (4 frags)
// of 16x16x32 bf16 MFMA, K = 256 in 8 steps.  acc[3][4] = 48 VGPR.
// Phase 1: copy 32 rows x 512 cols of xm (32 KB) into LDS tile
//   Bl[m = si*32+j][k = r*16+s].
// Phase 2: A-fragments stream from packed weights (L2-resident, coalesced
//   1 KiB wave loads), B-fragments from LDS.
// Epilogue: out[b][o][sp*64 + mm] — 64-contiguous coalesced f32 stores.
// (R8 configuration — measured best: 51.1 µs total.)
// ---------------------------------------------------------------------------
#define LDB 264   // 256 + 8 pad

__global__ __launch_bounds__(512, 4) void gemm_kernel(
        const short8* __restrict__ wbp,          // packed weights
        const __hip_bfloat16* __restrict__ xm,   // [B][H][W] mean image
        const float* __restrict__ bias,
        float* __restrict__ out) {               // [B][O][32][32]
    __shared__ short Bl[64][LDB];

    const int tid = threadIdx.x;
    const int b  = blockIdx.x >> 5;
    const int sp = (blockIdx.x >> 1) & 15;   // stripe pair (2 patch rows)
    const int oh = blockIdx.x & 1;           // o-half

    // ---- phase 1: 32 image rows x 512 cols bf16 -> LDS (4 short8/thread) ----
    {
        const int r   = tid >> 4;            // 0..31 image row within pair
        const int seg = tid & 15;            // 0..15, 32 shorts (64 B) each
        const int si  = r >> 4;              // stripe within pair
        const int r16 = r & 15;              // k-row within patch
        const short* src = reinterpret_cast<const short*>(
            xm + (size_t)b * HW + (size_t)(sp * 32 + r) * WIMG + seg * 32);
        #pragma unroll
        for (int q = 0; q < 4; ++q) {
            // col = seg*32 + q*8 -> patch j = seg*2 + (q>>1), s0 = (q&1)*8
            *reinterpret_cast<short8*>(
                &Bl[si * 32 + seg * 2 + (q >> 1)][r16 * 16 + (q & 1) * 8]) =
                *reinterpret_cast<const short8*>(src + q * 8);
        }
    }
    __syncthreads();

    // ---- phase 2: MFMA ----
    const int lane = tid & 63;
    const int wv   = tid >> 6;           // 0..7
    const int lrow = lane & 15;
    const int lg   = lane >> 4;

    f32x4 acc[3][4] = {};
    // global 16-row weight tile index: base_ot = (oh*384 + wv*48)/16
    const short8* wp = wbp + (size_t)(oh * 24 + wv * 3) * 8 * 64 + lane;

    #pragma unroll
    for (int kk = 0; kk < 8; ++kk) {
        short8 af[3], bf[4];
        #pragma unroll
        for (int fo = 0; fo < 3; ++fo)
            af[fo] = wp[(size_t)(fo * 8 + kk) * 64];
        #pragma unroll
        for (int fm = 0; fm < 4; ++fm)
            bf[fm] = *reinterpret_cast<const short8*>(&Bl[fm * 16 + lrow][kk * 32 + lg * 8]);
        #pragma unroll
        for (int fo = 0; fo < 3; ++fo)
            #pragma unroll
            for (int fm = 0; fm < 4; ++fm)
                acc[fo][fm] = __builtin_amdgcn_mfma_f32_16x16x32_bf16(af[fo], bf[fm], acc[fo][fm], 0, 0, 0);
    }

    // ---- epilogue: D row = o ((lane>>4)*4 + reg), col = m (lane&15) ----
    float* ob = out + (size_t)b * OCH * NPATCH + sp * 64;
    #pragma unroll
    for (int fo = 0; fo < 3; ++fo) {
        const int obase = oh * 384 + wv * 48 + fo * 16 + lg * 4;
        #pragma unroll
        for (int r = 0; r < 4; ++r) {
            const int o = obase + r;
            const float bv = bias[o];
            float* orow = ob + (size_t)o * NPATCH;
            #pragma unroll
            for (int fm = 0; fm < 4; ++fm)
                orow[fm * 16 + lrow] = acc[fo][fm][r] + bv;
        }
    }
}

// ---------------------------------------------------------------------------
extern "C" void kernel_launch(void* const* d_in, const int* in_sizes, int n_in,
                              void* d_out, int out_size, void* d_ws, size_t ws_size,
                              hipStream_t stream) {
    const float* x    = (const float*)d_in[0];
    const float* w    = (const float*)d_in[1];
    const float* bias = (const float*)d_in[2];
    float* out = (float*)d_out;

    __hip_bfloat16* xm = (__hip_bfloat16*)d_ws;                                   // 8 MiB
    short8* wbp = (short8*)((char*)d_ws + (size_t)BATCH * HW * 2);                // 384 KiB

    mean_pack_kernel<<<MEAN_BLOCKS + PACK_BLOCKS, 256, 0, stream>>>(x, xm, w, wbp);
    gemm_kernel<<<512, 512, 0, stream>>>(wbp, xm, bias, out);
}